// Round 1
// baseline (1194.153 us; speedup 1.0000x reference)
//
#include <hip/hip_runtime.h>

#define B_ 8
#define C_ 3
#define H_ 512
#define W_ 1024
#define H2_ 256
#define W2_ 512
#define GAMMA_ 50.0f

// acc layout (doubles in d_ws):
// 0: pm2_sum   (half-res photometric, both dirs)
// 1: ddx2_sum  (half-res smooth x, both disps)
// 2: ddy2_sum  (half-res smooth y, both disps)
// 3: pm_sum    (full-res photometric, both dirs)
// 4: ddx_sum   (full-res smooth x)
// 5: ddy_sum   (full-res smooth y)
// 6: ssim_sum  (both pairs)

template <int NV>
__device__ __forceinline__ void reduce_and_accumulate(float (&v)[NV], double* acc,
                                                      const int (&aidx)[NV]) {
    __shared__ float sred[NV][8];
    const int lane = threadIdx.x & 63;
    const int wave = threadIdx.x >> 6;
#pragma unroll
    for (int o = 32; o > 0; o >>= 1)
#pragma unroll
        for (int q = 0; q < NV; q++) v[q] += __shfl_down(v[q], o, 64);
    if (lane == 0)
#pragma unroll
        for (int q = 0; q < NV; q++) sred[q][wave] = v[q];
    __syncthreads();
    if (threadIdx.x == 0) {
        const int nw = (blockDim.x + 63) >> 6;
#pragma unroll
        for (int q = 0; q < NV; q++) {
            float s = 0.f;
            for (int w = 0; w < nw; w++) s += sred[q][w];
            atomicAdd(&acc[aidx[q]], (double)s);
        }
    }
}

__global__ void init_acc(double* acc) {
    if (threadIdx.x < 7) acc[threadIdx.x] = 0.0;
}

// ---------------- half-res: pm_d2 (both dirs) + smooth_d2 (both disps) --------------
__global__ __launch_bounds__(256) void half_kernel(const float* __restrict__ dL,
                                                   const float* __restrict__ dR,
                                                   const float* __restrict__ iL,
                                                   const float* __restrict__ iR,
                                                   double* acc) {
    const int gid = blockIdx.x * blockDim.x + threadIdx.x;
    float pm = 0.f, sx = 0.f, sy = 0.f;
    if (gid < B_ * H2_ * W2_) {
        const int x = gid % W2_;
        const int y = (gid / W2_) % H2_;
        const int b = gid / (W2_ * H2_);
        const int HW = H2_ * W2_;
        const int p = gid;  // (b*H2_+y)*W2_+x
        const int base = ((b * C_) * H2_ + y) * W2_;  // channel 0 row base + 0
        // left: warp img_rd2 with disp_ld2, x_dist=-1, compare to img_ld2
        {
            float d = dL[p];
            float xn = fminf(fmaxf((float)x - d, 0.f), (float)(W2_ - 1));
            float xf = floorf(xn);
            float wx = xn - xf;
            int x0 = (int)xf;
            int x1 = min(x0 + 1, W2_ - 1);
#pragma unroll
            for (int c = 0; c < C_; c++) {
                const float* src = iR + base + c * HW;
                float v = src[x0] * (1.f - wx) + src[x1] * wx;
                pm += fabsf(v - iL[base + c * HW + x]);
            }
        }
        // right: warp img_ld2 with disp_rd2, x_dist=+1, compare to img_rd2
        {
            float d = dR[p];
            float xn = fminf(fmaxf((float)x + d, 0.f), (float)(W2_ - 1));
            float xf = floorf(xn);
            float wx = xn - xf;
            int x0 = (int)xf;
            int x1 = min(x0 + 1, W2_ - 1);
#pragma unroll
            for (int c = 0; c < C_; c++) {
                const float* src = iL + base + c * HW;
                float v = src[x0] * (1.f - wx) + src[x1] * wx;
                pm += fabsf(v - iR[base + c * HW + x]);
            }
        }
        // smooth x
        if (x < W2_ - 1) {
            float ddl = fabsf(dL[p] - dL[p + 1]);
            float ddr = fabsf(dR[p] - dR[p + 1]);
            float il = fabsf(iL[base + x] - iL[base + x + 1]) +
                       fabsf(iL[base + HW + x] - iL[base + HW + x + 1]) +
                       fabsf(iL[base + 2 * HW + x] - iL[base + 2 * HW + x + 1]);
            float ir = fabsf(iR[base + x] - iR[base + x + 1]) +
                       fabsf(iR[base + HW + x] - iR[base + HW + x + 1]) +
                       fabsf(iR[base + 2 * HW + x] - iR[base + 2 * HW + x + 1]);
            sx += ddl * expf(-GAMMA_ * (il * (1.f / 3.f)));
            sx += ddr * expf(-GAMMA_ * (ir * (1.f / 3.f)));
        }
        // smooth y
        if (y < H2_ - 1) {
            float ddl = fabsf(dL[p] - dL[p + W2_]);
            float ddr = fabsf(dR[p] - dR[p + W2_]);
            float il = fabsf(iL[base + x] - iL[base + W2_ + x]) +
                       fabsf(iL[base + HW + x] - iL[base + HW + W2_ + x]) +
                       fabsf(iL[base + 2 * HW + x] - iL[base + 2 * HW + W2_ + x]);
            float ir = fabsf(iR[base + x] - iR[base + W2_ + x]) +
                       fabsf(iR[base + HW + x] - iR[base + HW + W2_ + x]) +
                       fabsf(iR[base + 2 * HW + x] - iR[base + 2 * HW + W2_ + x]);
            sy += ddl * expf(-GAMMA_ * (il * (1.f / 3.f)));
            sy += ddr * expf(-GAMMA_ * (ir * (1.f / 3.f)));
        }
    }
    float vals[3] = {pm, sx, sy};
    const int aidx[3] = {0, 1, 2};
    reduce_and_accumulate<3>(vals, acc, aidx);
}

// ---------------- full-res smooth (both disps) --------------
__global__ __launch_bounds__(256) void smooth_full_kernel(const float* __restrict__ dL,
                                                          const float* __restrict__ dR,
                                                          const float* __restrict__ iL,
                                                          const float* __restrict__ iR,
                                                          double* acc) {
    const int gid = blockIdx.x * blockDim.x + threadIdx.x;
    float sx = 0.f, sy = 0.f;
    if (gid < B_ * H_ * W_) {
        const int x = gid % W_;
        const int y = (gid / W_) % H_;
        const int b = gid / (W_ * H_);
        const int HW = H_ * W_;
        const int p = gid;
        const int base = ((b * C_) * H_ + y) * W_;
        if (x < W_ - 1) {
            float ddl = fabsf(dL[p] - dL[p + 1]);
            float ddr = fabsf(dR[p] - dR[p + 1]);
            float il = fabsf(iL[base + x] - iL[base + x + 1]) +
                       fabsf(iL[base + HW + x] - iL[base + HW + x + 1]) +
                       fabsf(iL[base + 2 * HW + x] - iL[base + 2 * HW + x + 1]);
            float ir = fabsf(iR[base + x] - iR[base + x + 1]) +
                       fabsf(iR[base + HW + x] - iR[base + HW + x + 1]) +
                       fabsf(iR[base + 2 * HW + x] - iR[base + 2 * HW + x + 1]);
            sx += ddl * expf(-GAMMA_ * (il * (1.f / 3.f)));
            sx += ddr * expf(-GAMMA_ * (ir * (1.f / 3.f)));
        }
        if (y < H_ - 1) {
            float ddl = fabsf(dL[p] - dL[p + W_]);
            float ddr = fabsf(dR[p] - dR[p + W_]);
            float il = fabsf(iL[base + x] - iL[base + W_ + x]) +
                       fabsf(iL[base + HW + x] - iL[base + HW + W_ + x]) +
                       fabsf(iL[base + 2 * HW + x] - iL[base + 2 * HW + W_ + x]);
            float ir = fabsf(iR[base + x] - iR[base + W_ + x]) +
                       fabsf(iR[base + HW + x] - iR[base + HW + W_ + x]) +
                       fabsf(iR[base + 2 * HW + x] - iR[base + 2 * HW + W_ + x]);
            sy += ddl * expf(-GAMMA_ * (il * (1.f / 3.f)));
            sy += ddr * expf(-GAMMA_ * (ir * (1.f / 3.f)));
        }
    }
    float vals[2] = {sx, sy};
    const int aidx[2] = {4, 5};
    reduce_and_accumulate<2>(vals, acc, aidx);
}

// ---------------- SSIM + full-res pm, tiled, warp-on-the-fly --------------
#define TH 16
#define TW 64
#define HWH (TH + 10)
#define HWW (TW + 10)

__global__ __launch_bounds__(256) void ssim_pm_kernel(const float* __restrict__ img_l,
                                                      const float* __restrict__ img_r,
                                                      const float* __restrict__ disp_l,
                                                      const float* __restrict__ disp_r,
                                                      double* acc) {
    __shared__ float sA[HWH][HWW];
    __shared__ float sB[HWH][HWW];
    __shared__ float vA[TH][HWW], vB[TH][HWW], vAA[TH][HWW], vBB[TH][HWW], vAB[TH][HWW];

    const int z = blockIdx.z;
    const int pair = z / (B_ * C_);
    const int bc = z % (B_ * C_);
    const int b = bc / C_;
    const int c = bc % C_;
    const float* samp = (pair == 0) ? img_r : img_l;
    const float* targ = (pair == 0) ? img_l : img_r;
    const float* disp = (pair == 0) ? disp_l : disp_r;
    const float sign = (pair == 0) ? -1.f : 1.f;

    const int x0t = blockIdx.x * TW;
    const int y0t = blockIdx.y * TH;

    float g[11];
    {
        float s = 0.f;
#pragma unroll
        for (int i = 0; i < 11; i++) {
            float xx = (float)(i - 5);
            g[i] = expf(-(xx * xx) / 4.5f);
            s += g[i];
        }
        float inv = 1.f / s;
#pragma unroll
        for (int i = 0; i < 11; i++) g[i] *= inv;
    }

    const int chanBase = (b * C_ + c) * H_ * W_;

    // load halo: b = target, a = warp(samp, disp) computed on the fly
    for (int idx = threadIdx.x; idx < HWH * HWW; idx += blockDim.x) {
        const int i = idx / HWW;
        const int j = idx % HWW;
        const int iy = y0t + i - 5;
        const int ix = x0t + j - 5;
        float av = 0.f, bv = 0.f;
        if (iy >= 0 && iy < H_ && ix >= 0 && ix < W_) {
            const int rowbase = chanBase + iy * W_;
            bv = targ[rowbase + ix];
            float d = disp[(b * H_ + iy) * W_ + ix];
            float xn = fminf(fmaxf((float)ix + sign * d, 0.f), (float)(W_ - 1));
            float xf = floorf(xn);
            float wx = xn - xf;
            int xi = (int)xf;
            int x1 = min(xi + 1, W_ - 1);
            av = samp[rowbase + xi] * (1.f - wx) + samp[rowbase + x1] * wx;
        }
        sA[i][j] = av;
        sB[i][j] = bv;
    }
    __syncthreads();

    // vertical Gaussian on 5 fields
    for (int idx = threadIdx.x; idx < TH * HWW; idx += blockDim.x) {
        const int r = idx / HWW;
        const int j = idx % HWW;
        float a_s = 0.f, b_s = 0.f, aa = 0.f, bb = 0.f, ab = 0.f;
#pragma unroll
        for (int k = 0; k < 11; k++) {
            float a = sA[r + k][j];
            float bq = sB[r + k][j];
            a_s += g[k] * a;
            b_s += g[k] * bq;
            aa += g[k] * a * a;
            bb += g[k] * bq * bq;
            ab += g[k] * a * bq;
        }
        vA[r][j] = a_s;
        vB[r][j] = b_s;
        vAA[r][j] = aa;
        vBB[r][j] = bb;
        vAB[r][j] = ab;
    }
    __syncthreads();

    // horizontal Gaussian + SSIM map + photometric L1 at centers
    float ssim_loc = 0.f, pm_loc = 0.f;
    for (int idx = threadIdx.x; idx < TH * TW; idx += blockDim.x) {
        const int r = idx / TW;
        const int cx = idx % TW;
        float mu1 = 0.f, mu2 = 0.f, m11 = 0.f, m22 = 0.f, m12 = 0.f;
#pragma unroll
        for (int k = 0; k < 11; k++) {
            mu1 += g[k] * vA[r][cx + k];
            mu2 += g[k] * vB[r][cx + k];
            m11 += g[k] * vAA[r][cx + k];
            m22 += g[k] * vBB[r][cx + k];
            m12 += g[k] * vAB[r][cx + k];
        }
        const float C1 = 1e-4f, C2 = 9e-4f;
        float mu1sq = mu1 * mu1, mu2sq = mu2 * mu2, mu12 = mu1 * mu2;
        float s1 = m11 - mu1sq, s2 = m22 - mu2sq, s12 = m12 - mu12;
        float num = (2.f * mu12 + C1) * (2.f * s12 + C2);
        float den = (mu1sq + mu2sq + C1) * (s1 + s2 + C2);
        ssim_loc += num / den;
        pm_loc += fabsf(sA[r + 5][cx + 5] - sB[r + 5][cx + 5]);
    }
    float vals[2] = {ssim_loc, pm_loc};
    const int aidx[2] = {6, 3};
    reduce_and_accumulate<2>(vals, acc, aidx);
}

__global__ void finalize_kernel(const double* __restrict__ acc, float* __restrict__ out) {
    if (threadIdx.x == 0 && blockIdx.x == 0) {
        const double N2 = (double)B_ * C_ * H2_ * W2_;
        const double Nx2 = (double)B_ * H2_ * (W2_ - 1);
        const double Ny2 = (double)B_ * (H2_ - 1) * W2_;
        const double N1 = (double)B_ * C_ * H_ * W_;
        const double Nx1 = (double)B_ * H_ * (W_ - 1);
        const double Ny1 = (double)B_ * (H_ - 1) * W_;
        double pm_d2 = acc[0] / N2;
        double smooth_d2 = acc[1] / Nx2 + acc[2] / Ny2;
        double pm = acc[3] / N1;
        double smooth = acc[4] / Nx1 + acc[5] / Ny1;
        double ssim_loss = 1.0 - acc[6] / (2.0 * N1);
        double full = pm_d2 + 0.1 * smooth_d2 + pm + ssim_loss + 0.1 * smooth;
        double mon = 5.0 * pm + ssim_loss;
        out[0] = (float)full;
        out[1] = (float)mon;
    }
}

extern "C" void kernel_launch(void* const* d_in, const int* in_sizes, int n_in,
                              void* d_out, int out_size, void* d_ws, size_t ws_size,
                              hipStream_t stream) {
    const float* disp_l = (const float*)d_in[0];
    const float* disp_r = (const float*)d_in[1];
    const float* disp_ld2 = (const float*)d_in[2];
    const float* disp_rd2 = (const float*)d_in[3];
    const float* img_l = (const float*)d_in[4];
    const float* img_r = (const float*)d_in[5];
    const float* img_ld2 = (const float*)d_in[6];
    const float* img_rd2 = (const float*)d_in[7];
    double* acc = (double*)d_ws;
    float* out = (float*)d_out;

    hipLaunchKernelGGL(init_acc, dim3(1), dim3(64), 0, stream, acc);

    const int n2 = B_ * H2_ * W2_;
    hipLaunchKernelGGL(half_kernel, dim3((n2 + 255) / 256), dim3(256), 0, stream,
                       disp_ld2, disp_rd2, img_ld2, img_rd2, acc);

    const int n1 = B_ * H_ * W_;
    hipLaunchKernelGGL(smooth_full_kernel, dim3((n1 + 255) / 256), dim3(256), 0, stream,
                       disp_l, disp_r, img_l, img_r, acc);

    dim3 grid(W_ / TW, H_ / TH, 2 * B_ * C_);
    hipLaunchKernelGGL(ssim_pm_kernel, grid, dim3(256), 0, stream,
                       img_l, img_r, disp_l, disp_r, acc);

    hipLaunchKernelGGL(finalize_kernel, dim3(1), dim3(1), 0, stream, acc, out);
}

// Round 2
// 480.406 us; speedup vs baseline: 2.4857x; 2.4857x over previous
//
#include <hip/hip_runtime.h>

#define B_ 8
#define C_ 3
#define H_ 512
#define W_ 1024
#define H2_ 256
#define W2_ 512
#define GAMMA_ 50.0f
#define NSUB 4

// acc layout (doubles in d_ws): quantity q, sub-slot s -> acc[q*NSUB+s], 28 doubles total
// q: 0 pm2, 1 ddx2, 2 ddy2, 3 pm, 4 ddx, 5 ddy, 6 ssim

template <int NV>
__device__ __forceinline__ void reduce_acc(float (&v)[NV], double* acc, const int (&qidx)[NV]) {
    __shared__ float sred[NV][4];
    const int lane = threadIdx.x & 63;
    const int wave = threadIdx.x >> 6;
#pragma unroll
    for (int o = 32; o > 0; o >>= 1)
#pragma unroll
        for (int q = 0; q < NV; q++) v[q] += __shfl_down(v[q], o, 64);
    if (lane == 0)
#pragma unroll
        for (int q = 0; q < NV; q++) sred[q][wave] = v[q];
    __syncthreads();
    if (threadIdx.x == 0) {
        const int sub = blockIdx.x & (NSUB - 1);
#pragma unroll
        for (int q = 0; q < NV; q++) {
            float s = sred[q][0] + sred[q][1] + sred[q][2] + sred[q][3];
            atomicAdd(&acc[qidx[q] * NSUB + sub], (double)s);
        }
    }
}

__global__ void init_acc(double* acc) {
    if (threadIdx.x < 7 * NSUB) acc[threadIdx.x] = 0.0;
}

// ---------------- half-res: pm_d2 + smooth_d2, grid-stride --------------
__global__ __launch_bounds__(256) void half_kernel(const float* __restrict__ dL,
                                                   const float* __restrict__ dR,
                                                   const float* __restrict__ iL,
                                                   const float* __restrict__ iR,
                                                   double* acc) {
    float pm = 0.f, sx = 0.f, sy = 0.f;
    const int total = B_ * H2_ * W2_;
    for (int gid = blockIdx.x * blockDim.x + threadIdx.x; gid < total;
         gid += gridDim.x * blockDim.x) {
        const int x = gid % W2_;
        const int y = (gid / W2_) % H2_;
        const int b = gid / (W2_ * H2_);
        const int HW = H2_ * W2_;
        const int p = gid;
        const int base = ((b * C_) * H2_ + y) * W2_;
        {
            float d = dL[p];
            float xn = fminf(fmaxf((float)x - d, 0.f), (float)(W2_ - 1));
            float xf = floorf(xn);
            float wx = xn - xf;
            int x0 = (int)xf;
            int x1 = min(x0 + 1, W2_ - 1);
#pragma unroll
            for (int c = 0; c < C_; c++) {
                const float* src = iR + base + c * HW;
                float v = src[x0] * (1.f - wx) + src[x1] * wx;
                pm += fabsf(v - iL[base + c * HW + x]);
            }
        }
        {
            float d = dR[p];
            float xn = fminf(fmaxf((float)x + d, 0.f), (float)(W2_ - 1));
            float xf = floorf(xn);
            float wx = xn - xf;
            int x0 = (int)xf;
            int x1 = min(x0 + 1, W2_ - 1);
#pragma unroll
            for (int c = 0; c < C_; c++) {
                const float* src = iL + base + c * HW;
                float v = src[x0] * (1.f - wx) + src[x1] * wx;
                pm += fabsf(v - iR[base + c * HW + x]);
            }
        }
        if (x < W2_ - 1) {
            float ddl = fabsf(dL[p] - dL[p + 1]);
            float ddr = fabsf(dR[p] - dR[p + 1]);
            float il = fabsf(iL[base + x] - iL[base + x + 1]) +
                       fabsf(iL[base + HW + x] - iL[base + HW + x + 1]) +
                       fabsf(iL[base + 2 * HW + x] - iL[base + 2 * HW + x + 1]);
            float ir = fabsf(iR[base + x] - iR[base + x + 1]) +
                       fabsf(iR[base + HW + x] - iR[base + HW + x + 1]) +
                       fabsf(iR[base + 2 * HW + x] - iR[base + 2 * HW + x + 1]);
            sx += ddl * __expf(-GAMMA_ * (il * (1.f / 3.f)));
            sx += ddr * __expf(-GAMMA_ * (ir * (1.f / 3.f)));
        }
        if (y < H2_ - 1) {
            float ddl = fabsf(dL[p] - dL[p + W2_]);
            float ddr = fabsf(dR[p] - dR[p + W2_]);
            float il = fabsf(iL[base + x] - iL[base + W2_ + x]) +
                       fabsf(iL[base + HW + x] - iL[base + HW + W2_ + x]) +
                       fabsf(iL[base + 2 * HW + x] - iL[base + 2 * HW + W2_ + x]);
            float ir = fabsf(iR[base + x] - iR[base + W2_ + x]) +
                       fabsf(iR[base + HW + x] - iR[base + HW + W2_ + x]) +
                       fabsf(iR[base + 2 * HW + x] - iR[base + 2 * HW + W2_ + x]);
            sy += ddl * __expf(-GAMMA_ * (il * (1.f / 3.f)));
            sy += ddr * __expf(-GAMMA_ * (ir * (1.f / 3.f)));
        }
    }
    float vals[3] = {pm, sx, sy};
    const int qidx[3] = {0, 1, 2};
    reduce_acc<3>(vals, acc, qidx);
}

// ---------------- full-res smooth, grid-stride --------------
__global__ __launch_bounds__(256) void smooth_full_kernel(const float* __restrict__ dL,
                                                          const float* __restrict__ dR,
                                                          const float* __restrict__ iL,
                                                          const float* __restrict__ iR,
                                                          double* acc) {
    float sx = 0.f, sy = 0.f;
    const int total = B_ * H_ * W_;
    for (int gid = blockIdx.x * blockDim.x + threadIdx.x; gid < total;
         gid += gridDim.x * blockDim.x) {
        const int x = gid % W_;
        const int y = (gid / W_) % H_;
        const int b = gid / (W_ * H_);
        const int HW = H_ * W_;
        const int p = gid;
        const int base = ((b * C_) * H_ + y) * W_;
        if (x < W_ - 1) {
            float ddl = fabsf(dL[p] - dL[p + 1]);
            float ddr = fabsf(dR[p] - dR[p + 1]);
            float il = fabsf(iL[base + x] - iL[base + x + 1]) +
                       fabsf(iL[base + HW + x] - iL[base + HW + x + 1]) +
                       fabsf(iL[base + 2 * HW + x] - iL[base + 2 * HW + x + 1]);
            float ir = fabsf(iR[base + x] - iR[base + x + 1]) +
                       fabsf(iR[base + HW + x] - iR[base + HW + x + 1]) +
                       fabsf(iR[base + 2 * HW + x] - iR[base + 2 * HW + x + 1]);
            sx += ddl * __expf(-GAMMA_ * (il * (1.f / 3.f)));
            sx += ddr * __expf(-GAMMA_ * (ir * (1.f / 3.f)));
        }
        if (y < H_ - 1) {
            float ddl = fabsf(dL[p] - dL[p + W_]);
            float ddr = fabsf(dR[p] - dR[p + W_]);
            float il = fabsf(iL[base + x] - iL[base + W_ + x]) +
                       fabsf(iL[base + HW + x] - iL[base + HW + W_ + x]) +
                       fabsf(iL[base + 2 * HW + x] - iL[base + 2 * HW + W_ + x]);
            float ir = fabsf(iR[base + x] - iR[base + W_ + x]) +
                       fabsf(iR[base + HW + x] - iR[base + HW + W_ + x]) +
                       fabsf(iR[base + 2 * HW + x] - iR[base + 2 * HW + W_ + x]);
            sy += ddl * __expf(-GAMMA_ * (il * (1.f / 3.f)));
            sy += ddr * __expf(-GAMMA_ * (ir * (1.f / 3.f)));
        }
    }
    float vals[2] = {sx, sy};
    const int qidx[2] = {4, 5};
    reduce_acc<2>(vals, acc, qidx);
}

// ---------------- SSIM + full-res pm --------------
#define TH 16
#define TW 64
#define HWH (TH + 10)
#define HWW (TW + 10)

__global__ __launch_bounds__(256) void ssim_pm_kernel(const float* __restrict__ img_l,
                                                      const float* __restrict__ img_r,
                                                      const float* __restrict__ disp_l,
                                                      const float* __restrict__ disp_r,
                                                      double* acc) {
    __shared__ float2 sAB[HWH][HWW];   // (a, b) raw halo
    __shared__ float2 vMu[TH][HWW];    // (hA, hB) vertical-convolved
    __shared__ float2 vSq[TH][HWW];    // (hAA, hBB)
    __shared__ float vXc[TH][HWW];     // hAB

    const int b = blockIdx.z;
    const int x0t = blockIdx.x * TW;
    const int y0t = blockIdx.y * TH;
    const int tx = threadIdx.x & 63;
    const int wy = threadIdx.x >> 6;

    float g[11];
    {
        float s = 0.f;
#pragma unroll
        for (int i = 0; i < 11; i++) {
            float xx = (float)(i - 5);
            g[i] = expf(-(xx * xx) / 4.5f);
            s += g[i];
        }
        float inv = 1.f / s;
#pragma unroll
        for (int i = 0; i < 11; i++) g[i] *= inv;
    }

    float ssim_loc = 0.f, pm_loc = 0.f;

#pragma unroll 1
    for (int s = 0; s < 6; s++) {
        const int pair = (s < 3) ? 0 : 1;
        const int c = (s < 3) ? s : s - 3;
        const float* samp = (pair == 0) ? img_r : img_l;
        const float* targ = (pair == 0) ? img_l : img_r;
        const float* disp = (pair == 0) ? disp_l : disp_r;
        const float sign = (pair == 0) ? -1.f : 1.f;
        const int chanBase = (b * C_ + c) * H_ * W_;

        __syncthreads();  // protect LDS from previous slice readers

        // ---- halo load: b = target, a = warp(samp) on the fly ----
        for (int i = wy; i < HWH; i += 4) {
            const int iy = y0t + i - 5;
            const bool yok = (iy >= 0 && iy < H_);
            const int rowbase = chanBase + iy * W_;
            const int drow = (b * H_ + iy) * W_;
#pragma unroll
            for (int jb = 0; jb < 2; jb++) {
                const int j = tx + jb * 64;
                if (jb == 1 && j >= HWW) break;
                const int ix = x0t + j - 5;
                float av = 0.f, bv = 0.f;
                if (yok && ix >= 0 && ix < W_) {
                    bv = targ[rowbase + ix];
                    float d = disp[drow + ix];
                    float xn = fminf(fmaxf((float)ix + sign * d, 0.f), (float)(W_ - 1));
                    float xf = floorf(xn);
                    float wx = xn - xf;
                    int xi = (int)xf;
                    int x1 = min(xi + 1, W_ - 1);
                    av = samp[rowbase + xi] * (1.f - wx) + samp[rowbase + x1] * wx;
                }
                sAB[i][j] = make_float2(av, bv);
            }
        }
        __syncthreads();

        // ---- vertical Gaussian: 5 fields from (a,b) pairs ----
        for (int r = wy; r < TH; r += 4) {
#pragma unroll
            for (int jb = 0; jb < 2; jb++) {
                const int j = tx + jb * 64;
                if (jb == 1 && j >= HWW) break;
                float a_s = 0.f, b_s = 0.f, aa = 0.f, bb = 0.f, ab = 0.f;
#pragma unroll
                for (int k = 0; k < 11; k++) {
                    float2 p = sAB[r + k][j];
                    float ga = g[k] * p.x;
                    float gb = g[k] * p.y;
                    a_s += ga;
                    b_s += gb;
                    aa += ga * p.x;
                    bb += gb * p.y;
                    ab += ga * p.y;
                }
                vMu[r][j] = make_float2(a_s, b_s);
                vSq[r][j] = make_float2(aa, bb);
                vXc[r][j] = ab;
            }
        }
        __syncthreads();

        // ---- horizontal Gaussian + SSIM + photometric L1 ----
        for (int r = wy; r < TH; r += 4) {
            const int cx = tx;
            float mu1 = 0.f, mu2 = 0.f, m11 = 0.f, m22 = 0.f, m12 = 0.f;
#pragma unroll
            for (int k = 0; k < 11; k++) {
                float2 mu = vMu[r][cx + k];
                float2 sq = vSq[r][cx + k];
                float xc = vXc[r][cx + k];
                mu1 += g[k] * mu.x;
                mu2 += g[k] * mu.y;
                m11 += g[k] * sq.x;
                m22 += g[k] * sq.y;
                m12 += g[k] * xc;
            }
            const float C1 = 1e-4f, C2 = 9e-4f;
            float mu1sq = mu1 * mu1, mu2sq = mu2 * mu2, mu12 = mu1 * mu2;
            float s1 = m11 - mu1sq, s2 = m22 - mu2sq, s12 = m12 - mu12;
            float num = (2.f * mu12 + C1) * (2.f * s12 + C2);
            float den = (mu1sq + mu2sq + C1) * (s1 + s2 + C2);
            ssim_loc += num / den;
            float2 ctr = sAB[r + 5][cx + 5];
            pm_loc += fabsf(ctr.x - ctr.y);
        }
    }

    float vals[2] = {ssim_loc, pm_loc};
    const int qidx[2] = {6, 3};
    reduce_acc<2>(vals, acc, qidx);
}

__global__ void finalize_kernel(const double* __restrict__ acc, float* __restrict__ out) {
    if (threadIdx.x == 0 && blockIdx.x == 0) {
        double q[7];
        for (int i = 0; i < 7; i++) {
            q[i] = 0.0;
            for (int s = 0; s < NSUB; s++) q[i] += acc[i * NSUB + s];
        }
        const double N2 = (double)B_ * C_ * H2_ * W2_;
        const double Nx2 = (double)B_ * H2_ * (W2_ - 1);
        const double Ny2 = (double)B_ * (H2_ - 1) * W2_;
        const double N1 = (double)B_ * C_ * H_ * W_;
        const double Nx1 = (double)B_ * H_ * (W_ - 1);
        const double Ny1 = (double)B_ * (H_ - 1) * W_;
        double pm_d2 = q[0] / N2;
        double smooth_d2 = q[1] / Nx2 + q[2] / Ny2;
        double pm = q[3] / N1;
        double smooth = q[4] / Nx1 + q[5] / Ny1;
        double ssim_loss = 1.0 - q[6] / (2.0 * N1);
        double full = pm_d2 + 0.1 * smooth_d2 + pm + ssim_loss + 0.1 * smooth;
        double mon = 5.0 * pm + ssim_loss;
        out[0] = (float)full;
        out[1] = (float)mon;
    }
}

extern "C" void kernel_launch(void* const* d_in, const int* in_sizes, int n_in,
                              void* d_out, int out_size, void* d_ws, size_t ws_size,
                              hipStream_t stream) {
    const float* disp_l = (const float*)d_in[0];
    const float* disp_r = (const float*)d_in[1];
    const float* disp_ld2 = (const float*)d_in[2];
    const float* disp_rd2 = (const float*)d_in[3];
    const float* img_l = (const float*)d_in[4];
    const float* img_r = (const float*)d_in[5];
    const float* img_ld2 = (const float*)d_in[6];
    const float* img_rd2 = (const float*)d_in[7];
    double* acc = (double*)d_ws;
    float* out = (float*)d_out;

    hipLaunchKernelGGL(init_acc, dim3(1), dim3(64), 0, stream, acc);

    hipLaunchKernelGGL(half_kernel, dim3(1024), dim3(256), 0, stream,
                       disp_ld2, disp_rd2, img_ld2, img_rd2, acc);

    hipLaunchKernelGGL(smooth_full_kernel, dim3(2048), dim3(256), 0, stream,
                       disp_l, disp_r, img_l, img_r, acc);

    dim3 grid(W_ / TW, H_ / TH, B_);
    hipLaunchKernelGGL(ssim_pm_kernel, grid, dim3(256), 0, stream,
                       img_l, img_r, disp_l, disp_r, acc);

    hipLaunchKernelGGL(finalize_kernel, dim3(1), dim3(1), 0, stream, acc, out);
}

// Round 3
// 301.590 us; speedup vs baseline: 3.9595x; 1.5929x over previous
//
#include <hip/hip_runtime.h>

#define B_ 8
#define C_ 3
#define H_ 512
#define W_ 1024
#define H2_ 256
#define W2_ 512
#define GAMMA_ 50.0f
#define NSUB 4

// acc layout (doubles in d_ws): quantity q, sub-slot s -> acc[q*NSUB+s], 28 doubles
// q: 0 pm2, 1 ddx2, 2 ddy2, 3 pm, 4 ddx, 5 ddy, 6 ssim

template <int NV>
__device__ __forceinline__ void reduce_acc(float (&v)[NV], double* acc, const int (&qidx)[NV]) {
    __shared__ float sred[NV][4];
    const int lane = threadIdx.x & 63;
    const int wave = threadIdx.x >> 6;
#pragma unroll
    for (int o = 32; o > 0; o >>= 1)
#pragma unroll
        for (int q = 0; q < NV; q++) v[q] += __shfl_down(v[q], o, 64);
    if (lane == 0)
#pragma unroll
        for (int q = 0; q < NV; q++) sred[q][wave] = v[q];
    __syncthreads();
    if (threadIdx.x == 0) {
        const int sub = blockIdx.x & (NSUB - 1);
#pragma unroll
        for (int q = 0; q < NV; q++) {
            float s = sred[q][0] + sred[q][1] + sred[q][2] + sred[q][3];
            atomicAdd(&acc[qidx[q] * NSUB + sub], (double)s);
        }
    }
}

__global__ void init_acc(double* acc) {
    if (threadIdx.x < 7 * NSUB) acc[threadIdx.x] = 0.0;
}

// ---------------- half-res: pm_d2 + smooth_d2, x4-coarsened --------------
__global__ __launch_bounds__(256) void half_kernel(const float* __restrict__ dL,
                                                   const float* __restrict__ dR,
                                                   const float* __restrict__ iL,
                                                   const float* __restrict__ iR,
                                                   double* acc) {
    const int W4 = W2_ >> 2;
    const int total = B_ * H2_ * W4;
    const int HW = H2_ * W2_;
    float pm = 0.f, sx = 0.f, sy = 0.f;
    for (int gid = blockIdx.x * blockDim.x + threadIdx.x; gid < total;
         gid += gridDim.x * blockDim.x) {
        const int xq = gid % W4;
        const int x4 = xq << 2;
        const int yz = gid / W4;
        const int y = yz % H2_;
        const int b = yz / H2_;
        const int p0 = (b * H2_ + y) * W2_ + x4;
        const int ib = ((b * C_) * H2_ + y) * W2_ + x4;  // ch-0 target row at x4
        const bool lastx = (x4 + 4 == W2_);
        const bool lasty = (y == H2_ - 1);

        float dl[5], dr[5];
        *(float4*)dl = *(const float4*)(dL + p0);
        *(float4*)dr = *(const float4*)(dR + p0);
        dl[4] = lastx ? 0.f : dL[p0 + 4];
        dr[4] = lastx ? 0.f : dR[p0 + 4];

        int xl0[4], xl1[4], xr0[4], xr1[4];
        float wxl[4], wxr[4];
#pragma unroll
        for (int i = 0; i < 4; i++) {
            float xn = fminf(fmaxf((float)(x4 + i) - dl[i], 0.f), (float)(W2_ - 1));
            float xf = floorf(xn);
            wxl[i] = xn - xf;
            xl0[i] = (int)xf;
            xl1[i] = xl0[i] + (xl0[i] < W2_ - 1 ? 1 : 0);
            float xm = fminf(fmaxf((float)(x4 + i) + dr[i], 0.f), (float)(W2_ - 1));
            float xg = floorf(xm);
            wxr[i] = xm - xg;
            xr0[i] = (int)xg;
            xr1[i] = xr0[i] + (xr0[i] < W2_ - 1 ? 1 : 0);
        }

        float axL[4] = {0, 0, 0, 0}, axR[4] = {0, 0, 0, 0};
        float ayL[4] = {0, 0, 0, 0}, ayR[4] = {0, 0, 0, 0};
#pragma unroll
        for (int ch = 0; ch < C_; ch++) {
            const float* pL = iL + ib + ch * HW;
            const float* pR = iR + ib + ch * HW;
            float vL[5], vR[5];
            *(float4*)vL = *(const float4*)pL;
            *(float4*)vR = *(const float4*)pR;
            vL[4] = lastx ? 0.f : pL[4];
            vR[4] = lastx ? 0.f : pR[4];
#pragma unroll
            for (int i = 0; i < 4; i++) {
                axL[i] += fabsf(vL[i] - vL[i + 1]);
                axR[i] += fabsf(vR[i] - vR[i + 1]);
            }
            if (!lasty) {
                float wLr[4], wRr[4];
                *(float4*)wLr = *(const float4*)(pL + W2_);
                *(float4*)wRr = *(const float4*)(pR + W2_);
#pragma unroll
                for (int i = 0; i < 4; i++) {
                    ayL[i] += fabsf(vL[i] - wLr[i]);
                    ayR[i] += fabsf(vR[i] - wRr[i]);
                }
            }
            // warps: left warps iR, right warps iL (row start = ib - x4 + ch*HW)
            const float* gLrow = iR + ib - x4 + ch * HW;
            const float* gRrow = iL + ib - x4 + ch * HW;
#pragma unroll
            for (int i = 0; i < 4; i++) {
                float wv = gLrow[xl0[i]] * (1.f - wxl[i]) + gLrow[xl1[i]] * wxl[i];
                pm += fabsf(wv - vL[i]);
                float wv2 = gRrow[xr0[i]] * (1.f - wxr[i]) + gRrow[xr1[i]] * wxr[i];
                pm += fabsf(wv2 - vR[i]);
            }
        }
        const int nx = lastx ? 3 : 4;
#pragma unroll
        for (int i = 0; i < 4; i++) {
            if (i < nx) {
                sx += fabsf(dl[i] - dl[i + 1]) * __expf(-GAMMA_ * (axL[i] * (1.f / 3.f)));
                sx += fabsf(dr[i] - dr[i + 1]) * __expf(-GAMMA_ * (axR[i] * (1.f / 3.f)));
            }
        }
        if (!lasty) {
            float el[4], er[4];
            *(float4*)el = *(const float4*)(dL + p0 + W2_);
            *(float4*)er = *(const float4*)(dR + p0 + W2_);
#pragma unroll
            for (int i = 0; i < 4; i++) {
                sy += fabsf(dl[i] - el[i]) * __expf(-GAMMA_ * (ayL[i] * (1.f / 3.f)));
                sy += fabsf(dr[i] - er[i]) * __expf(-GAMMA_ * (ayR[i] * (1.f / 3.f)));
            }
        }
    }
    float vals[3] = {pm, sx, sy};
    const int qidx[3] = {0, 1, 2};
    reduce_acc<3>(vals, acc, qidx);
}

// ---------------- full-res smooth, x4-coarsened --------------
__global__ __launch_bounds__(256) void smooth_full_kernel(const float* __restrict__ dL,
                                                          const float* __restrict__ dR,
                                                          const float* __restrict__ iL,
                                                          const float* __restrict__ iR,
                                                          double* acc) {
    const int W4 = W_ >> 2;
    const int total = B_ * H_ * W4;
    const int HW = H_ * W_;
    float sx = 0.f, sy = 0.f;
    for (int gid = blockIdx.x * blockDim.x + threadIdx.x; gid < total;
         gid += gridDim.x * blockDim.x) {
        const int xq = gid % W4;
        const int x4 = xq << 2;
        const int yz = gid / W4;
        const int y = yz % H_;
        const int b = yz / H_;
        const int p0 = (b * H_ + y) * W_ + x4;
        const int ib = ((b * C_) * H_ + y) * W_ + x4;
        const bool lastx = (x4 + 4 == W_);
        const bool lasty = (y == H_ - 1);

        float axL[4] = {0, 0, 0, 0}, axR[4] = {0, 0, 0, 0};
        float ayL[4] = {0, 0, 0, 0}, ayR[4] = {0, 0, 0, 0};
#pragma unroll
        for (int ch = 0; ch < C_; ch++) {
            const float* pL = iL + ib + ch * HW;
            const float* pR = iR + ib + ch * HW;
            float vL[5], vR[5];
            *(float4*)vL = *(const float4*)pL;
            *(float4*)vR = *(const float4*)pR;
            vL[4] = lastx ? 0.f : pL[4];
            vR[4] = lastx ? 0.f : pR[4];
#pragma unroll
            for (int i = 0; i < 4; i++) {
                axL[i] += fabsf(vL[i] - vL[i + 1]);
                axR[i] += fabsf(vR[i] - vR[i + 1]);
            }
            if (!lasty) {
                float wLr[4], wRr[4];
                *(float4*)wLr = *(const float4*)(pL + W_);
                *(float4*)wRr = *(const float4*)(pR + W_);
#pragma unroll
                for (int i = 0; i < 4; i++) {
                    ayL[i] += fabsf(vL[i] - wLr[i]);
                    ayR[i] += fabsf(vR[i] - wRr[i]);
                }
            }
        }
        float dl[5], dr[5];
        *(float4*)dl = *(const float4*)(dL + p0);
        *(float4*)dr = *(const float4*)(dR + p0);
        dl[4] = lastx ? 0.f : dL[p0 + 4];
        dr[4] = lastx ? 0.f : dR[p0 + 4];
        const int nx = lastx ? 3 : 4;
#pragma unroll
        for (int i = 0; i < 4; i++) {
            if (i < nx) {
                sx += fabsf(dl[i] - dl[i + 1]) * __expf(-GAMMA_ * (axL[i] * (1.f / 3.f)));
                sx += fabsf(dr[i] - dr[i + 1]) * __expf(-GAMMA_ * (axR[i] * (1.f / 3.f)));
            }
        }
        if (!lasty) {
            float el[4], er[4];
            *(float4*)el = *(const float4*)(dL + p0 + W_);
            *(float4*)er = *(const float4*)(dR + p0 + W_);
#pragma unroll
            for (int i = 0; i < 4; i++) {
                sy += fabsf(dl[i] - el[i]) * __expf(-GAMMA_ * (ayL[i] * (1.f / 3.f)));
                sy += fabsf(dr[i] - er[i]) * __expf(-GAMMA_ * (ayR[i] * (1.f / 3.f)));
            }
        }
    }
    float vals[2] = {sx, sy};
    const int qidx[2] = {4, 5};
    reduce_acc<2>(vals, acc, qidx);
}

// ---------------- SSIM + full-res pm, register-tiled separable conv --------------
#define TH 16
#define TW 64
#define HALO_H (TH + 10)          // 26
#define HALO_W (TW + 10)          // 74
#define HALO_N (HALO_H * HALO_W)  // 1924
#define VW 75                     // padded row for vF (bank decorrelation)

__global__ __launch_bounds__(256) void ssim_pm_kernel(const float* __restrict__ img_l,
                                                      const float* __restrict__ img_r,
                                                      const float* __restrict__ disp_l,
                                                      const float* __restrict__ disp_r,
                                                      double* acc) {
    __shared__ float2 sAB[HALO_N];    // (a=warp, b=target) raw halo   15392 B
    __shared__ float4 vF4[TH * VW];   // (vA, vB, vAA, vBB)            19200 B
    __shared__ float vF1[TH * VW];    // vAB                            4800 B

    const int z = blockIdx.z;
    const int b = z >> 1;
    const int pair = z & 1;
    const float* samp = (pair == 0) ? img_r : img_l;
    const float* targ = (pair == 0) ? img_l : img_r;
    const float* disp = (pair == 0) ? disp_l : disp_r;
    const float sign = (pair == 0) ? -1.f : 1.f;

    const int x0t = blockIdx.x * TW;
    const int y0t = blockIdx.y * TH;

    float g[11];
    {
        float s = 0.f;
#pragma unroll
        for (int i = 0; i < 11; i++) {
            float xx = (float)(i - 5);
            g[i] = expf(-(xx * xx) / 4.5f);
            s += g[i];
        }
        float inv = 1.f / s;
#pragma unroll
        for (int i = 0; i < 11; i++) g[i] *= inv;
    }

    // ---- phase 0: warp coordinates, once per (pair) — shared by all 3 channels ----
    int riy[8], gxa[8], gxb[8];
    float wxs[8];
    {
        const int bHW = b * (H_ * W_);
#pragma unroll
        for (int it = 0; it < 8; ++it) {
            const int idx = threadIdx.x + 256 * it;
            riy[it] = -1;
            if (idx < HALO_N) {
                const int i = idx / HALO_W;
                const int j = idx - i * HALO_W;
                const int iy = y0t + i - 5;
                const int ix = x0t + j - 5;
                if (iy >= 0 && iy < H_ && ix >= 0 && ix < W_) {
                    const int r = iy * W_ + ix;
                    riy[it] = r;
                    const float d = disp[bHW + r];
                    float xn = fminf(fmaxf((float)ix + sign * d, 0.f), (float)(W_ - 1));
                    float xf = floorf(xn);
                    wxs[it] = xn - xf;
                    const int xi = (int)xf;
                    gxa[it] = iy * W_ + xi;
                    gxb[it] = gxa[it] + (xi < W_ - 1 ? 1 : 0);
                }
            }
        }
    }

    float ssim_loc = 0.f, pm_loc = 0.f;

#pragma unroll 1
    for (int c = 0; c < C_; ++c) {
        const int cb = (b * C_ + c) * (H_ * W_);
        __syncthreads();  // protect LDS from previous channel's readers

        // ---- halo: b = target, a = warp(samp) via cached coords ----
#pragma unroll
        for (int it = 0; it < 8; ++it) {
            const int idx = threadIdx.x + 256 * it;
            if (idx < HALO_N) {
                float av = 0.f, bv = 0.f;
                if (riy[it] >= 0) {
                    bv = targ[cb + riy[it]];
                    const float wx = wxs[it];
                    av = samp[cb + gxa[it]] * (1.f - wx) + samp[cb + gxb[it]] * wx;
                }
                sAB[idx] = make_float2(av, bv);
            }
        }
        __syncthreads();

        // ---- vertical pass: each task = (col j, 4 output rows), 14-tap slide ----
#pragma unroll
        for (int it = 0; it < 2; ++it) {
            const int t = threadIdx.x + 256 * it;
            if (t < 4 * HALO_W) {
                const int q = t / HALO_W;
                const int j = t - q * HALO_W;
                const int r0 = q * 4;
                float am[4], bm[4], aas[4], bbs[4], abz[4];
#pragma unroll
                for (int i = 0; i < 4; i++) { am[i] = bm[i] = aas[i] = bbs[i] = abz[i] = 0.f; }
#pragma unroll
                for (int k = 0; k < 14; ++k) {
                    const float2 p = sAB[(r0 + k) * HALO_W + j];
                    const float aa = p.x * p.x, bb = p.y * p.y, ab = p.x * p.y;
#pragma unroll
                    for (int i = 0; i < 4; ++i) {
                        if (k >= i && k <= i + 10) {
                            const float w = g[k - i];
                            am[i] += w * p.x;
                            bm[i] += w * p.y;
                            aas[i] += w * aa;
                            bbs[i] += w * bb;
                            abz[i] += w * ab;
                        }
                    }
                }
#pragma unroll
                for (int i = 0; i < 4; ++i) {
                    vF4[(r0 + i) * VW + j] = make_float4(am[i], bm[i], aas[i], bbs[i]);
                    vF1[(r0 + i) * VW + j] = abz[i];
                }
            }
        }
        __syncthreads();

        // ---- horizontal pass: task = (row r, 4 output cols), 14-tap slide ----
        {
            const int t = threadIdx.x;
            const int r = t & 15;
            const int c0 = (t >> 4) << 2;
            float m1[4], m2[4], q11[4], q22[4], q12[4];
#pragma unroll
            for (int i = 0; i < 4; i++) { m1[i] = m2[i] = q11[i] = q22[i] = q12[i] = 0.f; }
#pragma unroll
            for (int k = 0; k < 14; ++k) {
                const float4 f = vF4[r * VW + c0 + k];
                const float xc = vF1[r * VW + c0 + k];
#pragma unroll
                for (int i = 0; i < 4; ++i) {
                    if (k >= i && k <= i + 10) {
                        const float w = g[k - i];
                        m1[i] += w * f.x;
                        m2[i] += w * f.y;
                        q11[i] += w * f.z;
                        q22[i] += w * f.w;
                        q12[i] += w * xc;
                    }
                }
            }
#pragma unroll
            for (int i = 0; i < 4; ++i) {
                const float C1 = 1e-4f, C2 = 9e-4f;
                const float mu1 = m1[i], mu2 = m2[i];
                const float mu1sq = mu1 * mu1, mu2sq = mu2 * mu2, mu12 = mu1 * mu2;
                const float s1 = q11[i] - mu1sq, s2 = q22[i] - mu2sq, s12 = q12[i] - mu12;
                ssim_loc += (2.f * mu12 + C1) * (2.f * s12 + C2) /
                            ((mu1sq + mu2sq + C1) * (s1 + s2 + C2));
                const float2 ctr = sAB[(r + 5) * HALO_W + c0 + 5 + i];
                pm_loc += fabsf(ctr.x - ctr.y);
            }
        }
    }

    float vals[2] = {ssim_loc, pm_loc};
    const int qidx[2] = {6, 3};
    reduce_acc<2>(vals, acc, qidx);
}

__global__ void finalize_kernel(const double* __restrict__ acc, float* __restrict__ out) {
    if (threadIdx.x == 0 && blockIdx.x == 0) {
        double q[7];
        for (int i = 0; i < 7; i++) {
            q[i] = 0.0;
            for (int s = 0; s < NSUB; s++) q[i] += acc[i * NSUB + s];
        }
        const double N2 = (double)B_ * C_ * H2_ * W2_;
        const double Nx2 = (double)B_ * H2_ * (W2_ - 1);
        const double Ny2 = (double)B_ * (H2_ - 1) * W2_;
        const double N1 = (double)B_ * C_ * H_ * W_;
        const double Nx1 = (double)B_ * H_ * (W_ - 1);
        const double Ny1 = (double)B_ * (H_ - 1) * W_;
        double pm_d2 = q[0] / N2;
        double smooth_d2 = q[1] / Nx2 + q[2] / Ny2;
        double pm = q[3] / N1;
        double smooth = q[4] / Nx1 + q[5] / Ny1;
        double ssim_loss = 1.0 - q[6] / (2.0 * N1);
        double full = pm_d2 + 0.1 * smooth_d2 + pm + ssim_loss + 0.1 * smooth;
        double mon = 5.0 * pm + ssim_loss;
        out[0] = (float)full;
        out[1] = (float)mon;
    }
}

extern "C" void kernel_launch(void* const* d_in, const int* in_sizes, int n_in,
                              void* d_out, int out_size, void* d_ws, size_t ws_size,
                              hipStream_t stream) {
    const float* disp_l = (const float*)d_in[0];
    const float* disp_r = (const float*)d_in[1];
    const float* disp_ld2 = (const float*)d_in[2];
    const float* disp_rd2 = (const float*)d_in[3];
    const float* img_l = (const float*)d_in[4];
    const float* img_r = (const float*)d_in[5];
    const float* img_ld2 = (const float*)d_in[6];
    const float* img_rd2 = (const float*)d_in[7];
    double* acc = (double*)d_ws;
    float* out = (float*)d_out;

    hipLaunchKernelGGL(init_acc, dim3(1), dim3(64), 0, stream, acc);

    hipLaunchKernelGGL(half_kernel, dim3(1024), dim3(256), 0, stream,
                       disp_ld2, disp_rd2, img_ld2, img_rd2, acc);

    hipLaunchKernelGGL(smooth_full_kernel, dim3(2048), dim3(256), 0, stream,
                       disp_l, disp_r, img_l, img_r, acc);

    dim3 grid(W_ / TW, H_ / TH, 2 * B_);
    hipLaunchKernelGGL(ssim_pm_kernel, grid, dim3(256), 0, stream,
                       img_l, img_r, disp_l, disp_r, acc);

    hipLaunchKernelGGL(finalize_kernel, dim3(1), dim3(1), 0, stream, acc, out);
}